// Round 10
// baseline (279.734 us; speedup 1.0000x reference)
//
#include <hip/hip_runtime.h>
#include <stdint.h>

// Problem constants
#define B_   2
#define SQ   2048
#define H    1024
#define NH   16
#define HN   64
#define T_TOK 4096          // sq*b tokens
#define N3H  3072           // 3*h

typedef __bf16 bf16x8 __attribute__((ext_vector_type(8)));
typedef float  f32x4  __attribute__((ext_vector_type(4)));
typedef float  f32x16 __attribute__((ext_vector_type(16)));

#define MFMA16(a, b, c) __builtin_amdgcn_mfma_f32_16x16x32_bf16((a), (b), (c), 0, 0, 0)
#define MFMA32(a, b, c) __builtin_amdgcn_mfma_f32_32x32x16_bf16((a), (b), (c), 0, 0, 0)

// s_waitcnt lgkmcnt(0), vmcnt/expcnt left open (intrinsic form).
#define LGKM_DRAIN() do { \
  __builtin_amdgcn_s_waitcnt(0xC07F); \
  __builtin_amdgcn_wave_barrier(); \
} while (0)

__device__ __forceinline__ uint16_t f2bf_u(float f) {
  union { float f; uint32_t u; } v; v.f = f;
  uint32_t u = v.u;
  u += 0x7fffu + ((u >> 16) & 1u);   // RNE (no NaN inputs here)
  return (uint16_t)(u >> 16);
}

// packed f32 pair -> bf16 pair via compiler-native casts (RNE).
__device__ __forceinline__ uint32_t pk2(float a, float b) {
  union { __bf16 h[2]; uint32_t u; } r;
  r.h[0] = (__bf16)a;
  r.h[1] = (__bf16)b;
  return r.u;
}

__device__ __forceinline__ bf16x8 ldb8(const uint16_t* p) {
  return *reinterpret_cast<const bf16x8*>(p);
}

// async global->LDS, 16B per lane. LDS dest = wave-uniform base + lane*16.
__device__ __forceinline__ void gll16(const uint16_t* g, uint16_t* l) {
  __builtin_amdgcn_global_load_lds(
      (const __attribute__((address_space(1))) uint32_t*)g,
      (__attribute__((address_space(3))) uint32_t*)l, 16, 0, 0);
}

// ---------------------------------------------------------------------------
// Kernel 1: fp32 -> bf16, 4 elements/thread.  (unchanged)
// ---------------------------------------------------------------------------
__global__ __launch_bounds__(256) void convert_kernel(
    const float* __restrict__ x, const float* __restrict__ wqkv,
    const float* __restrict__ wproj,
    uint16_t* __restrict__ xb, uint16_t* __restrict__ wqkvb,
    uint16_t* __restrict__ wprojb) {
  const int XT4 = (T_TOK * H) / 4;   // 1048576
  const int WQ4 = (N3H * H) / 4;     // 786432
  int i4 = blockIdx.x * 256 + threadIdx.x;
  const float* src;
  uint16_t* dst;
  if (i4 < XT4) {
    int i = i4 * 4;
    int t = i >> 10, c = i & 1023;
    int bi = t & 1, s = t >> 1;
    src = x + (bi * SQ + s) * H + c;
    dst = xb + i;
  } else if (i4 < XT4 + WQ4) {
    int j = (i4 - XT4) * 4;
    src = wqkv + j; dst = wqkvb + j;
  } else {
    int j = (i4 - XT4 - WQ4) * 4;
    src = wproj + j; dst = wprojb + j;
  }
  float4 v = *(const float4*)src;
  ushort4 o;
  o.x = f2bf_u(v.x); o.y = f2bf_u(v.y); o.z = f2bf_u(v.z); o.w = f2bf_u(v.w);
  *(ushort4*)dst = o;
}

// ---------------------------------------------------------------------------
// Kernel 2: QKV GEMM.  (round-7 version, HW-verified: depth-3 counted-vmcnt
// pipeline; Q pre-scaled, Vtb s-permuted epilogue)
// ---------------------------------------------------------------------------
__global__ __launch_bounds__(256) void gemm_qkv_kernel(
    const uint16_t* __restrict__ xb, const uint16_t* __restrict__ wb,
    uint16_t* __restrict__ Qb, uint16_t* __restrict__ Kb,
    uint16_t* __restrict__ Vtb) {
  const int lane = threadIdx.x & 63;
  const int wave = threadIdx.x >> 6;
  const int quad = lane >> 4, l16 = lane & 15;
  const int wm = wave >> 1, wn = wave & 1;
  const int row0 = blockIdx.y * 128, col0 = blockIdx.x * 128;

  // buf b at smem + b*16384: {sA 128x32, sB 128x32}.  3 bufs = 48 KB.
  // Epilogue W (4 x 9728 B = 38912 B) overlays them after the loop.
  __shared__ __align__(16) char smem[3 * 16384];
  uint16_t* W = (uint16_t*)(smem) + wave * (64 * 76);

  const int lrow = lane >> 2;        // 0..15
  const int lk   = (lane & 3) * 8;   // k-chunk (8 elems = 16B)

  f32x4 acc[4][4];
#pragma unroll
  for (int i = 0; i < 4; ++i)
#pragma unroll
    for (int j = 0; j < 4; ++j) acc[i][j] = (f32x4){0.f, 0.f, 0.f, 0.f};

  auto STAGE = [&](int b, int k0) {   // 4 gll16 per wave
    uint16_t* sA = (uint16_t*)(smem + b * 16384);
    uint16_t* sB = sA + 4096;
#pragma unroll
    for (int c = 0; c < 2; ++c) {
      int g = c * 4 + wave;
      gll16(xb + (size_t)(row0 + g * 16 + lrow) * H + k0 + lk, sA + g * 512);
      gll16(wb + (size_t)(col0 + g * 16 + lrow) * H + k0 + lk, sB + g * 512);
    }
  };

  auto COMPUTE = [&](int b) {
    const uint16_t* sA = (const uint16_t*)(smem + b * 16384);
    const uint16_t* sB = sA + 4096;
    bf16x8 af[4], bfr[4];
#pragma unroll
    for (int mt = 0; mt < 4; ++mt)
      af[mt] = ldb8(sA + (wm * 64 + mt * 16 + l16) * 32 + quad * 8);
#pragma unroll
    for (int nt = 0; nt < 4; ++nt)
      bfr[nt] = ldb8(sB + (wn * 64 + nt * 16 + l16) * 32 + quad * 8);
    __builtin_amdgcn_s_setprio(1);
#pragma unroll
    for (int mt = 0; mt < 4; ++mt)
#pragma unroll
      for (int nt = 0; nt < 4; ++nt)
        acc[mt][nt] = MFMA16(af[mt], bfr[nt], acc[mt][nt]);
    __builtin_amdgcn_s_setprio(0);
    asm volatile("s_waitcnt lgkmcnt(0)" ::: "memory");   // reads complete
    __builtin_amdgcn_s_barrier();                        // before buf reuse
  };

  STAGE(0, 0);
  STAGE(1, 32);
  STAGE(2, 64);

#pragma unroll 3
  for (int t = 0; t < 30; ++t) {
    asm volatile("s_waitcnt vmcnt(8)" ::: "memory");   // oldest tile landed
    __builtin_amdgcn_s_barrier();
    COMPUTE(t % 3);
    if (t < 29) STAGE(t % 3, (t + 3) * 32);
  }
  asm volatile("s_waitcnt vmcnt(4)" ::: "memory");
  __builtin_amdgcn_s_barrier();
  COMPUTE(0);                                          // tile 30
  asm volatile("s_waitcnt vmcnt(0)" ::: "memory");
  __builtin_amdgcn_s_barrier();
  COMPUTE(1);                                          // tile 31 (trailing
                                                       // barrier guards W)

  const int c0 = col0 + wn * 64;       // 64-aligned
  const int cm = c0 >> 6;              // 0..47
  const int hd = cm / 3;               // head (compile-time magic-mul)
  const int which = cm - hd * 3;       // 0=Q 1=K 2=V
  const int t0 = row0 + wm * 64;

  if (which < 2) {
    const float qs = (which == 0) ? 0.18033688f : 1.0f;   // 0.125*log2(e) for Q
#pragma unroll
    for (int mt = 0; mt < 4; ++mt)
#pragma unroll
      for (int nt = 0; nt < 4; ++nt)
#pragma unroll
        for (int r = 0; r < 4; ++r)
          W[(mt * 16 + quad * 4 + r) * 76 + nt * 16 + l16] = f2bf_u(acc[mt][nt][r] * qs);
    LGKM_DRAIN();
    uint16_t* dstb = (which == 0) ? Qb : Kb;
    const int t8 = lane >> 3, d0 = (lane & 7) * 8;
#pragma unroll
    for (int it = 0; it < 8; ++it) {
      int tl = it * 8 + t8;
      int t = t0 + tl;
      int s = t >> 1;
      int n = (t & 1) * NH + hd;
      bf16x8 vv = ldb8(W + tl * 76 + d0);
      *(bf16x8*)(dstb + (size_t)(n * SQ + s) * HN + d0) = vv;
    }
  } else {
    // V: LDS tile [d][bi*32 + s_local] (logical s order), stride 76
    uint32_t* W32 = (uint32_t*)W;
#pragma unroll
    for (int mt = 0; mt < 4; ++mt)
#pragma unroll
      for (int nt = 0; nt < 4; ++nt) {
        int base = (nt * 16 + l16) * 76 + mt * 8 + quad * 2;   // even
        W32[base >> 1] =
            (uint32_t)f2bf_u(acc[mt][nt][0]) | ((uint32_t)f2bf_u(acc[mt][nt][2]) << 16);
        W32[(base >> 1) + 16] =
            (uint32_t)f2bf_u(acc[mt][nt][1]) | ((uint32_t)f2bf_u(acc[mt][nt][3]) << 16);
      }
    LGKM_DRAIN();
    // store with s-permutation pi(s) = swap bits 2,3 of s (self-inverse):
    // dest chunk sc (8 s') pulls source 4-groups {sb+4h+0..3, sb+4h+8..11}
    const int dl = lane >> 3;                 // 0..7
    const int bi = (lane >> 2) & 1;
    const int sc = (lane & 3) * 8;
    const int s0 = (row0 >> 1) + wm * 32;
    const int n = bi * NH + hd;
    const int sb = sc & ~15;
    const int hh = (sc >> 3) & 1;
#pragma unroll
    for (int it = 0; it < 8; ++it) {
      int d = it * 8 + dl;
      const uint16_t* Wr = W + d * 76 + bi * 32 + sb + hh * 4;
      union { uint64_t q[2]; bf16x8 v; } vv;
      vv.q[0] = *(const uint64_t*)(Wr);       // logical s: sb + 4h + 0..3
      vv.q[1] = *(const uint64_t*)(Wr + 8);   // logical s: sb + 4h + 8..11
      *(bf16x8*)(Vtb + (size_t)(n * HN + d) * SQ + s0 + sc) = vv.v;
    }
  }
}

// ---------------------------------------------------------------------------
// Kernel 3: flash attention.  Round-10: occupancy over pipelining.
// Single-buffered K/V staging (no dbuf) -> LDS 33.8 KB -> 4 blocks/CU ->
// 32 waves/CU (8/SIMD, the cap).  Per-iter staging stall is hidden by TLP
// from the other 3 resident blocks (m114).  __launch_bounds__(512,8) pins
// VGPR <= 64 (r8 core measured 52).  Compute core = r8 verbatim.
// ---------------------------------------------------------------------------
__global__ __launch_bounds__(512, 8) void attn_kernel(
    const uint16_t* __restrict__ Qb, const uint16_t* __restrict__ Kb,
    const uint16_t* __restrict__ Vtb, uint16_t* __restrict__ ctxb) {
  const int lane = threadIdx.x & 63;
  const int wave = threadIdx.x >> 6;        // 0..7
  const int l32 = lane & 31;
  const int hi  = lane >> 5;
  const int wq = wave & 3;                  // q-subtile (32 rows)
  const int hf = wave >> 2;                 // k-range half

  const int bid = blockIdx.x;               // 512 blocks
  const int xcd = bid & 7, slot = bid >> 3; // id%8 -> XCD round-robin
  const int head = xcd * 4 + (slot >> 4);   // 4 heads pinned per XCD
  const int qt   = slot & 15;
  const int q0w  = qt * 128 + wq * 32;

  const uint16_t* Qh = Qb + (size_t)head * SQ * HN;
  const uint16_t* Kh = Kb + (size_t)head * SQ * HN;
  const uint16_t* Vh = Vtb + (size_t)head * HN * SQ;

  // LDS: staging sK(hf)=smem+hf*16384 {K 8KB + V 8KB} = 32 KB total.
  // Epilogue cacc[4][64][33] f32 (33792 B) overlays staging; each wave's
  // ctile reuses its OWN cacc slice (read-then-write, same wave, drained).
  __shared__ __align__(16) char smem[33792];
  float (*cacc)[64][33] = (float(*)[64][33])smem;

  const int lr8 = lane >> 3, lc8 = lane & 7;
  const int sc8 = (lc8 - lr8) & 7;          // logical chunk this lane fetches

  // persistent Q fragments (B operand): col q = q0w + l32, k-half = hi
  bf16x8 qf[4];
#pragma unroll
  for (int dc = 0; dc < 4; ++dc)
    qf[dc] = ldb8(Qh + (size_t)(q0w + l32) * HN + dc * 16 + hi * 8);

  f32x16 acc[2];
#pragma unroll
  for (int dt = 0; dt < 2; ++dt)
#pragma unroll
    for (int e = 0; e < 16; ++e) acc[dt][e] = 0.f;
  float lrun = 0.f;

  uint16_t* sK = (uint16_t*)(smem + hf * 16384);
  uint16_t* sV = sK + 4096;

  // stage one K tile + one Vt tile (this wave's 16 rows of each)
  auto STAGE = [&](int kt) {
    const int kbase = (hf * 16 + kt) * 64;
#pragma unroll
    for (int j = 0; j < 2; ++j) {
      int rr = wq * 16 + j * 8;
      gll16(Kh + (size_t)(kbase + rr + lr8) * HN + sc8 * 8, sK + rr * 64);
      gll16(Vh + (size_t)(rr + lr8) * SQ + kbase + sc8 * 8, sV + rr * 64);
    }
  };

  // full kt compute: QK^T, softmax, PV for both ktiles (r8 core, verbatim)
  auto KTCOMP = [&]() {
#pragma unroll
    for (int ktile = 0; ktile < 2; ++ktile) {
      f32x16 s;
#pragma unroll
      for (int e = 0; e < 16; ++e) s[e] = 0.f;
      __builtin_amdgcn_s_setprio(1);
#pragma unroll
      for (int dc = 0; dc < 4; ++dc) {
        bf16x8 kf = ldb8(sK + (ktile * 32 + l32) * 64 + ((dc * 2 + hi + l32) & 7) * 8);
        s = MFMA32(kf, qf[dc], s);
      }
      __builtin_amdgcn_s_setprio(0);
      uint32_t c[8];
#pragma unroll
      for (int i = 0; i < 8; ++i) {
        float p0 = __builtin_amdgcn_exp2f(s[2 * i]);
        float p1 = __builtin_amdgcn_exp2f(s[2 * i + 1]);
        lrun += p0;
        lrun += p1;
        c[i] = pk2(p0, p1);
      }
      union { uint32_t u[4]; bf16x8 v; } pa0, pa1;
#pragma unroll
      for (int x = 0; x < 4; ++x) { pa0.u[x] = c[x]; pa1.u[x] = c[4 + x]; }
      __builtin_amdgcn_s_setprio(1);
#pragma unroll
      for (int dt = 0; dt < 2; ++dt) {
        bf16x8 v0 = ldb8(sV + (dt * 32 + l32) * 64 + ((ktile * 4 + 0 + hi + l32) & 7) * 8);
        bf16x8 v1 = ldb8(sV + (dt * 32 + l32) * 64 + ((ktile * 4 + 2 + hi + l32) & 7) * 8);
        acc[dt] = MFMA32(pa0.v, v0, acc[dt]);
        acc[dt] = MFMA32(pa1.v, v1, acc[dt]);
      }
      __builtin_amdgcn_s_setprio(0);
    }
  };

  for (int kt = 0; kt < 16; ++kt) {
    STAGE(kt);
    asm volatile("s_waitcnt vmcnt(0)" ::: "memory");   // my stage landed
    __builtin_amdgcn_s_barrier();                      // all stages landed
    KTCOMP();
    asm volatile("s_waitcnt lgkmcnt(0)" ::: "memory"); // my frag reads done
    __builtin_amdgcn_s_barrier();                      // before overwrite
  }

  float lrunf = lrun;

  // --- k-split combine (linear: no max-tracking) via aliased LDS ---
  if (hf) {
    float* dst = &cacc[wq][lane][0];
#pragma unroll
    for (int dt = 0; dt < 2; ++dt)
#pragma unroll
      for (int e = 0; e < 16; ++e) dst[dt * 16 + e] = acc[dt][e];
    dst[32] = lrunf;
  }
  __syncthreads();
  if (hf) return;
  {
    const float* src = &cacc[wq][lane][0];
#pragma unroll
    for (int dt = 0; dt < 2; ++dt)
#pragma unroll
      for (int e = 0; e < 16; ++e) acc[dt][e] += src[dt * 16 + e];
    lrunf += src[32];
  }
  LGKM_DRAIN();     // combine reads retired before ctile overwrites the slice

  // --- epilogue: cross-half rowsum, normalize, coalesced store via LDS ---
  float ls = lrunf + __shfl_xor(lrunf, 32);   // full rowsum for q = l32
  float rinv = __builtin_amdgcn_rcpf(ls);
  uint16_t* ctile = (uint16_t*)(smem + wq * 8448);   // own cacc slice
#pragma unroll
  for (int e = 0; e < 16; ++e) {
    int qe = (e & 3) + 8 * (e >> 2) + 4 * hi;   // q-row of this acc reg
    float rv = __shfl(rinv, qe);
    ctile[qe * 72 + l32]      = f2bf_u(acc[0][e] * rv);
    ctile[qe * 72 + 32 + l32] = f2bf_u(acc[1][e] * rv);
  }
  LGKM_DRAIN();
  {
    const int q8 = lane >> 3, d0 = (lane & 7) * 8;
    const int gcb = (head >> 1) * HN;
#pragma unroll
    for (int it = 0; it < 4; ++it) {
      int ql = it * 8 + q8;
      bf16x8 vv = ldb8(ctile + ql * 72 + d0);
      int row = 2 * (q0w + ql) + (head & 1);    // reference (nh,b) view scramble
      *(bf16x8*)(ctxb + (size_t)row * H + gcb + d0) = vv;
    }
  }
}

// ---------------------------------------------------------------------------
// Kernel 4: projection + bias.  (round-7 version: depth-3 counted-vmcnt)
// ---------------------------------------------------------------------------
__global__ __launch_bounds__(256) void gemm_proj_kernel(
    const uint16_t* __restrict__ ab, const uint16_t* __restrict__ wb,
    const float* __restrict__ bias, float* __restrict__ out) {
  const int lane = threadIdx.x & 63;
  const int wave = threadIdx.x >> 6;
  const int quad = lane >> 4, l16 = lane & 15;
  const int row0 = blockIdx.y * 128, col0 = blockIdx.x * 64;

  // buf b: sA 128x32 (8 KB) + sB 64x32 (4 KB) at smem + b*12288; 3 bufs.
  __shared__ __align__(16) char smem[3 * 12288];

  const int lrow = lane >> 2;
  const int lk   = (lane & 3) * 8;

  f32x4 acc[2][4];
#pragma unroll
  for (int i = 0; i < 2; ++i)
#pragma unroll
    for (int j = 0; j < 4; ++j) acc[i][j] = (f32x4){0.f, 0.f, 0.f, 0.f};

  auto STAGE = [&](int b, int k0) {   // 3 gll16 per wave
    uint16_t* sA = (uint16_t*)(smem + b * 12288);
    uint16_t* sB = sA + 4096;
#pragma unroll
    for (int c = 0; c < 2; ++c) {
      int g = c * 4 + wave;
      gll16(ab + (size_t)(row0 + g * 16 + lrow) * H + k0 + lk, sA + g * 512);
    }
    gll16(wb + (size_t)(col0 + wave * 16 + lrow) * H + k0 + lk, sB + wave * 512);
  };

  auto COMPUTE = [&](int b) {
    const uint16_t* sA = (const uint16_t*)(smem + b * 12288);
    const uint16_t* sB = sA + 4096;
    bf16x8 af[2], bfr[4];
#pragma unroll
    for (int mt = 0; mt < 2; ++mt)
      af[mt] = ldb8(sA + (wave * 32 + mt * 16 + l16) * 32 + quad * 8);
#pragma unroll
    for (int nt = 0; nt < 4; ++nt)
      bfr[nt] = ldb8(sB + (nt * 16 + l16) * 32 + quad * 8);
    __builtin_amdgcn_s_setprio(1);
#pragma unroll
    for (int mt = 0; mt < 2; ++mt)
#pragma unroll
      for (int nt = 0; nt < 4; ++nt)
        acc[mt][nt] = MFMA16(af[mt], bfr[nt], acc[mt][nt]);
    __builtin_amdgcn_s_setprio(0);
    asm volatile("s_waitcnt lgkmcnt(0)" ::: "memory");
    __builtin_amdgcn_s_barrier();
  };

  STAGE(0, 0);
  STAGE(1, 32);
  STAGE(2, 64);

#pragma unroll 3
  for (int t = 0; t < 30; ++t) {
    asm volatile("s_waitcnt vmcnt(6)" ::: "memory");   // oldest tile landed
    __builtin_amdgcn_s_barrier();
    COMPUTE(t % 3);
    if (t < 29) STAGE(t % 3, (t + 3) * 32);
  }
  asm volatile("s_waitcnt vmcnt(3)" ::: "memory");
  __builtin_amdgcn_s_barrier();
  COMPUTE(0);                                          // tile 30
  asm volatile("s_waitcnt vmcnt(0)" ::: "memory");
  __builtin_amdgcn_s_barrier();
  COMPUTE(1);                                          // tile 31

#pragma unroll
  for (int mt = 0; mt < 2; ++mt)
#pragma unroll
    for (int nt = 0; nt < 4; ++nt)
#pragma unroll
      for (int r = 0; r < 4; ++r) {
        int m = row0 + wave * 32 + mt * 16 + quad * 4 + r;  // t' = s*2+bi
        int c = col0 + nt * 16 + l16;
        int s = m >> 1, bi = m & 1;
        out[(size_t)(bi * SQ + s) * H + c] = acc[mt][nt][r] + bias[c];
      }
}

// ---------------------------------------------------------------------------
extern "C" void kernel_launch(void* const* d_in, const int* in_sizes, int n_in,
                              void* d_out, int out_size, void* d_ws, size_t ws_size,
                              hipStream_t stream) {
  const float* x     = (const float*)d_in[0];
  const float* wqkv  = (const float*)d_in[3];
  const float* wproj = (const float*)d_in[4];
  const float* bproj = (const float*)d_in[5];
  float* out = (float*)d_out;

  char* ws = (char*)d_ws;
  uint16_t* xb     = (uint16_t*)(ws);                        //  8 MB
  uint16_t* wqkvb  = (uint16_t*)(ws + (8ull  << 20));        //  6 MB
  uint16_t* wprojb = (uint16_t*)(ws + (14ull << 20));        //  2 MB
  uint16_t* Qb     = (uint16_t*)(ws + (16ull << 20));        //  8 MB [32][2048][64] (pre-scaled)
  uint16_t* Kb     = (uint16_t*)(ws + (24ull << 20));        //  8 MB [32][2048][64]
  uint16_t* Vtb    = (uint16_t*)(ws + (32ull << 20));        //  8 MB [32][64][2048] (s-permuted)
  uint16_t* ctxb   = (uint16_t*)(ws + (40ull << 20));        //  8 MB [4096][1024]

  convert_kernel<<<8192, 256, 0, stream>>>(x, wqkv, wproj, xb, wqkvb, wprojb);
  gemm_qkv_kernel<<<dim3(N3H / 128, T_TOK / 128), 256, 0, stream>>>(xb, wqkvb, Qb, Kb, Vtb);
  attn_kernel<<<512, 512, 0, stream>>>(Qb, Kb, Vtb, ctxb);
  gemm_proj_kernel<<<dim3(H / 64, T_TOK / 128), 256, 0, stream>>>(ctxb, wprojb, bproj, out);
}

// Round 11
// 214.253 us; speedup vs baseline: 1.3056x; 1.3056x over previous
//
#include <hip/hip_runtime.h>
#include <stdint.h>

// Problem constants
#define B_   2
#define SQ   2048
#define H    1024
#define NH   16
#define HN   64
#define T_TOK 4096          // sq*b tokens
#define N3H  3072           // 3*h

typedef __bf16 bf16x8 __attribute__((ext_vector_type(8)));
typedef float  f32x4  __attribute__((ext_vector_type(4)));
typedef float  f32x16 __attribute__((ext_vector_type(16)));

#define MFMA16(a, b, c) __builtin_amdgcn_mfma_f32_16x16x32_bf16((a), (b), (c), 0, 0, 0)
#define MFMA32(a, b, c) __builtin_amdgcn_mfma_f32_32x32x16_bf16((a), (b), (c), 0, 0, 0)

// s_waitcnt lgkmcnt(0), vmcnt/expcnt left open (intrinsic form).
#define LGKM_DRAIN() do { \
  __builtin_amdgcn_s_waitcnt(0xC07F); \
  __builtin_amdgcn_wave_barrier(); \
} while (0)

__device__ __forceinline__ uint16_t f2bf_u(float f) {
  union { float f; uint32_t u; } v; v.f = f;
  uint32_t u = v.u;
  u += 0x7fffu + ((u >> 16) & 1u);   // RNE (no NaN inputs here)
  return (uint16_t)(u >> 16);
}

// packed f32 pair -> bf16 pair via compiler-native casts (RNE).
__device__ __forceinline__ uint32_t pk2(float a, float b) {
  union { __bf16 h[2]; uint32_t u; } r;
  r.h[0] = (__bf16)a;
  r.h[1] = (__bf16)b;
  return r.u;
}

__device__ __forceinline__ bf16x8 ldb8(const uint16_t* p) {
  return *reinterpret_cast<const bf16x8*>(p);
}

// async global->LDS, 16B per lane. LDS dest = wave-uniform base + lane*16.
__device__ __forceinline__ void gll16(const uint16_t* g, uint16_t* l) {
  __builtin_amdgcn_global_load_lds(
      (const __attribute__((address_space(1))) uint32_t*)g,
      (__attribute__((address_space(3))) uint32_t*)l, 16, 0, 0);
}

// ---------------------------------------------------------------------------
// Kernel 1: fp32 -> bf16, 4 elements/thread.  (unchanged)
// ---------------------------------------------------------------------------
__global__ __launch_bounds__(256) void convert_kernel(
    const float* __restrict__ x, const float* __restrict__ wqkv,
    const float* __restrict__ wproj,
    uint16_t* __restrict__ xb, uint16_t* __restrict__ wqkvb,
    uint16_t* __restrict__ wprojb) {
  const int XT4 = (T_TOK * H) / 4;   // 1048576
  const int WQ4 = (N3H * H) / 4;     // 786432
  int i4 = blockIdx.x * 256 + threadIdx.x;
  const float* src;
  uint16_t* dst;
  if (i4 < XT4) {
    int i = i4 * 4;
    int t = i >> 10, c = i & 1023;
    int bi = t & 1, s = t >> 1;
    src = x + (bi * SQ + s) * H + c;
    dst = xb + i;
  } else if (i4 < XT4 + WQ4) {
    int j = (i4 - XT4) * 4;
    src = wqkv + j; dst = wqkvb + j;
  } else {
    int j = (i4 - XT4 - WQ4) * 4;
    src = wproj + j; dst = wprojb + j;
  }
  float4 v = *(const float4*)src;
  ushort4 o;
  o.x = f2bf_u(v.x); o.y = f2bf_u(v.y); o.z = f2bf_u(v.z); o.w = f2bf_u(v.w);
  *(ushort4*)dst = o;
}

// ---------------------------------------------------------------------------
// Kernel 2: QKV GEMM.  (round-7 version, HW-verified: depth-3 counted-vmcnt
// pipeline; Q pre-scaled, Vtb s-permuted epilogue)
// ---------------------------------------------------------------------------
__global__ __launch_bounds__(256) void gemm_qkv_kernel(
    const uint16_t* __restrict__ xb, const uint16_t* __restrict__ wb,
    uint16_t* __restrict__ Qb, uint16_t* __restrict__ Kb,
    uint16_t* __restrict__ Vtb) {
  const int lane = threadIdx.x & 63;
  const int wave = threadIdx.x >> 6;
  const int quad = lane >> 4, l16 = lane & 15;
  const int wm = wave >> 1, wn = wave & 1;
  const int row0 = blockIdx.y * 128, col0 = blockIdx.x * 128;

  // buf b at smem + b*16384: {sA 128x32, sB 128x32}.  3 bufs = 48 KB.
  // Epilogue W (4 x 9728 B = 38912 B) overlays them after the loop.
  __shared__ __align__(16) char smem[3 * 16384];
  uint16_t* W = (uint16_t*)(smem) + wave * (64 * 76);

  const int lrow = lane >> 2;        // 0..15
  const int lk   = (lane & 3) * 8;   // k-chunk (8 elems = 16B)

  f32x4 acc[4][4];
#pragma unroll
  for (int i = 0; i < 4; ++i)
#pragma unroll
    for (int j = 0; j < 4; ++j) acc[i][j] = (f32x4){0.f, 0.f, 0.f, 0.f};

  auto STAGE = [&](int b, int k0) {   // 4 gll16 per wave
    uint16_t* sA = (uint16_t*)(smem + b * 16384);
    uint16_t* sB = sA + 4096;
#pragma unroll
    for (int c = 0; c < 2; ++c) {
      int g = c * 4 + wave;
      gll16(xb + (size_t)(row0 + g * 16 + lrow) * H + k0 + lk, sA + g * 512);
      gll16(wb + (size_t)(col0 + g * 16 + lrow) * H + k0 + lk, sB + g * 512);
    }
  };

  auto COMPUTE = [&](int b) {
    const uint16_t* sA = (const uint16_t*)(smem + b * 16384);
    const uint16_t* sB = sA + 4096;
    bf16x8 af[4], bfr[4];
#pragma unroll
    for (int mt = 0; mt < 4; ++mt)
      af[mt] = ldb8(sA + (wm * 64 + mt * 16 + l16) * 32 + quad * 8);
#pragma unroll
    for (int nt = 0; nt < 4; ++nt)
      bfr[nt] = ldb8(sB + (wn * 64 + nt * 16 + l16) * 32 + quad * 8);
    __builtin_amdgcn_s_setprio(1);
#pragma unroll
    for (int mt = 0; mt < 4; ++mt)
#pragma unroll
      for (int nt = 0; nt < 4; ++nt)
        acc[mt][nt] = MFMA16(af[mt], bfr[nt], acc[mt][nt]);
    __builtin_amdgcn_s_setprio(0);
    asm volatile("s_waitcnt lgkmcnt(0)" ::: "memory");   // reads complete
    __builtin_amdgcn_s_barrier();                        // before buf reuse
  };

  STAGE(0, 0);
  STAGE(1, 32);
  STAGE(2, 64);

#pragma unroll 3
  for (int t = 0; t < 30; ++t) {
    asm volatile("s_waitcnt vmcnt(8)" ::: "memory");   // oldest tile landed
    __builtin_amdgcn_s_barrier();
    COMPUTE(t % 3);
    if (t < 29) STAGE(t % 3, (t + 3) * 32);
  }
  asm volatile("s_waitcnt vmcnt(4)" ::: "memory");
  __builtin_amdgcn_s_barrier();
  COMPUTE(0);                                          // tile 30
  asm volatile("s_waitcnt vmcnt(0)" ::: "memory");
  __builtin_amdgcn_s_barrier();
  COMPUTE(1);                                          // tile 31 (trailing
                                                       // barrier guards W)

  const int c0 = col0 + wn * 64;       // 64-aligned
  const int cm = c0 >> 6;              // 0..47
  const int hd = cm / 3;               // head (compile-time magic-mul)
  const int which = cm - hd * 3;       // 0=Q 1=K 2=V
  const int t0 = row0 + wm * 64;

  if (which < 2) {
    const float qs = (which == 0) ? 0.18033688f : 1.0f;   // 0.125*log2(e) for Q
#pragma unroll
    for (int mt = 0; mt < 4; ++mt)
#pragma unroll
      for (int nt = 0; nt < 4; ++nt)
#pragma unroll
        for (int r = 0; r < 4; ++r)
          W[(mt * 16 + quad * 4 + r) * 76 + nt * 16 + l16] = f2bf_u(acc[mt][nt][r] * qs);
    LGKM_DRAIN();
    uint16_t* dstb = (which == 0) ? Qb : Kb;
    const int t8 = lane >> 3, d0 = (lane & 7) * 8;
#pragma unroll
    for (int it = 0; it < 8; ++it) {
      int tl = it * 8 + t8;
      int t = t0 + tl;
      int s = t >> 1;
      int n = (t & 1) * NH + hd;
      bf16x8 vv = ldb8(W + tl * 76 + d0);
      *(bf16x8*)(dstb + (size_t)(n * SQ + s) * HN + d0) = vv;
    }
  } else {
    // V: LDS tile [d][bi*32 + s_local] (logical s order), stride 76
    uint32_t* W32 = (uint32_t*)W;
#pragma unroll
    for (int mt = 0; mt < 4; ++mt)
#pragma unroll
      for (int nt = 0; nt < 4; ++nt) {
        int base = (nt * 16 + l16) * 76 + mt * 8 + quad * 2;   // even
        W32[base >> 1] =
            (uint32_t)f2bf_u(acc[mt][nt][0]) | ((uint32_t)f2bf_u(acc[mt][nt][2]) << 16);
        W32[(base >> 1) + 16] =
            (uint32_t)f2bf_u(acc[mt][nt][1]) | ((uint32_t)f2bf_u(acc[mt][nt][3]) << 16);
      }
    LGKM_DRAIN();
    // store with s-permutation pi(s) = swap bits 2,3 of s (self-inverse):
    // dest chunk sc (8 s') pulls source 4-groups {sb+4h+0..3, sb+4h+8..11}
    const int dl = lane >> 3;                 // 0..7
    const int bi = (lane >> 2) & 1;
    const int sc = (lane & 3) * 8;
    const int s0 = (row0 >> 1) + wm * 32;
    const int n = bi * NH + hd;
    const int sb = sc & ~15;
    const int hh = (sc >> 3) & 1;
#pragma unroll
    for (int it = 0; it < 8; ++it) {
      int d = it * 8 + dl;
      const uint16_t* Wr = W + d * 76 + bi * 32 + sb + hh * 4;
      union { uint64_t q[2]; bf16x8 v; } vv;
      vv.q[0] = *(const uint64_t*)(Wr);       // logical s: sb + 4h + 0..3
      vv.q[1] = *(const uint64_t*)(Wr + 8);   // logical s: sb + 4h + 8..11
      *(bf16x8*)(Vtb + (size_t)(n * HN + d) * SQ + s0 + sc) = vv.v;
    }
  }
}

// ---------------------------------------------------------------------------
// Kernel 3: flash attention.  Round-11: round-10 structure (single-buffered
// staging, 33.8 KB LDS, 4 blocks/CU capacity) with the ONE change:
// __launch_bounds__(512, 6) instead of (512, 8).  R10's (512,8) made the
// compiler allocate 32 VGPR and spill acc to scratch (WRITE_SIZE 170 MB).
// At 6 waves/EU the cap is ~85 VGPR (core needs ~52); if the allocator
// lands <= 64, hardware still fits 8 waves/SIMD = 4 blocks/CU.
// ---------------------------------------------------------------------------
__global__ __launch_bounds__(512, 6) void attn_kernel(
    const uint16_t* __restrict__ Qb, const uint16_t* __restrict__ Kb,
    const uint16_t* __restrict__ Vtb, uint16_t* __restrict__ ctxb) {
  const int lane = threadIdx.x & 63;
  const int wave = threadIdx.x >> 6;        // 0..7
  const int l32 = lane & 31;
  const int hi  = lane >> 5;
  const int wq = wave & 3;                  // q-subtile (32 rows)
  const int hf = wave >> 2;                 // k-range half

  const int bid = blockIdx.x;               // 512 blocks
  const int xcd = bid & 7, slot = bid >> 3; // id%8 -> XCD round-robin
  const int head = xcd * 4 + (slot >> 4);   // 4 heads pinned per XCD
  const int qt   = slot & 15;
  const int q0w  = qt * 128 + wq * 32;

  const uint16_t* Qh = Qb + (size_t)head * SQ * HN;
  const uint16_t* Kh = Kb + (size_t)head * SQ * HN;
  const uint16_t* Vh = Vtb + (size_t)head * HN * SQ;

  // LDS: staging sK(hf)=smem+hf*16384 {K 8KB + V 8KB} = 32 KB total.
  // Epilogue cacc[4][64][33] f32 (33792 B) overlays staging; each wave's
  // ctile reuses its OWN cacc slice (read-then-write, same wave, drained).
  __shared__ __align__(16) char smem[33792];
  float (*cacc)[64][33] = (float(*)[64][33])smem;

  const int lr8 = lane >> 3, lc8 = lane & 7;
  const int sc8 = (lc8 - lr8) & 7;          // logical chunk this lane fetches

  // persistent Q fragments (B operand): col q = q0w + l32, k-half = hi
  bf16x8 qf[4];
#pragma unroll
  for (int dc = 0; dc < 4; ++dc)
    qf[dc] = ldb8(Qh + (size_t)(q0w + l32) * HN + dc * 16 + hi * 8);

  f32x16 acc[2];
#pragma unroll
  for (int dt = 0; dt < 2; ++dt)
#pragma unroll
    for (int e = 0; e < 16; ++e) acc[dt][e] = 0.f;
  float lrun = 0.f;

  uint16_t* sK = (uint16_t*)(smem + hf * 16384);
  uint16_t* sV = sK + 4096;

  // stage one K tile + one Vt tile (this wave's 16 rows of each)
  auto STAGE = [&](int kt) {
    const int kbase = (hf * 16 + kt) * 64;
#pragma unroll
    for (int j = 0; j < 2; ++j) {
      int rr = wq * 16 + j * 8;
      gll16(Kh + (size_t)(kbase + rr + lr8) * HN + sc8 * 8, sK + rr * 64);
      gll16(Vh + (size_t)(rr + lr8) * SQ + kbase + sc8 * 8, sV + rr * 64);
    }
  };

  // full kt compute: QK^T, softmax, PV for both ktiles (r8 core, verbatim)
  auto KTCOMP = [&]() {
#pragma unroll
    for (int ktile = 0; ktile < 2; ++ktile) {
      f32x16 s;
#pragma unroll
      for (int e = 0; e < 16; ++e) s[e] = 0.f;
      __builtin_amdgcn_s_setprio(1);
#pragma unroll
      for (int dc = 0; dc < 4; ++dc) {
        bf16x8 kf = ldb8(sK + (ktile * 32 + l32) * 64 + ((dc * 2 + hi + l32) & 7) * 8);
        s = MFMA32(kf, qf[dc], s);
      }
      __builtin_amdgcn_s_setprio(0);
      uint32_t c[8];
#pragma unroll
      for (int i = 0; i < 8; ++i) {
        float p0 = __builtin_amdgcn_exp2f(s[2 * i]);
        float p1 = __builtin_amdgcn_exp2f(s[2 * i + 1]);
        lrun += p0;
        lrun += p1;
        c[i] = pk2(p0, p1);
      }
      union { uint32_t u[4]; bf16x8 v; } pa0, pa1;
#pragma unroll
      for (int x = 0; x < 4; ++x) { pa0.u[x] = c[x]; pa1.u[x] = c[4 + x]; }
      __builtin_amdgcn_s_setprio(1);
#pragma unroll
      for (int dt = 0; dt < 2; ++dt) {
        bf16x8 v0 = ldb8(sV + (dt * 32 + l32) * 64 + ((ktile * 4 + 0 + hi + l32) & 7) * 8);
        bf16x8 v1 = ldb8(sV + (dt * 32 + l32) * 64 + ((ktile * 4 + 2 + hi + l32) & 7) * 8);
        acc[dt] = MFMA32(pa0.v, v0, acc[dt]);
        acc[dt] = MFMA32(pa1.v, v1, acc[dt]);
      }
      __builtin_amdgcn_s_setprio(0);
    }
  };

  for (int kt = 0; kt < 16; ++kt) {
    STAGE(kt);
    asm volatile("s_waitcnt vmcnt(0)" ::: "memory");   // my stage landed
    __builtin_amdgcn_s_barrier();                      // all stages landed
    KTCOMP();
    asm volatile("s_waitcnt lgkmcnt(0)" ::: "memory"); // my frag reads done
    __builtin_amdgcn_s_barrier();                      // before overwrite
  }

  float lrunf = lrun;

  // --- k-split combine (linear: no max-tracking) via aliased LDS ---
  if (hf) {
    float* dst = &cacc[wq][lane][0];
#pragma unroll
    for (int dt = 0; dt < 2; ++dt)
#pragma unroll
      for (int e = 0; e < 16; ++e) dst[dt * 16 + e] = acc[dt][e];
    dst[32] = lrunf;
  }
  __syncthreads();
  if (hf) return;
  {
    const float* src = &cacc[wq][lane][0];
#pragma unroll
    for (int dt = 0; dt < 2; ++dt)
#pragma unroll
      for (int e = 0; e < 16; ++e) acc[dt][e] += src[dt * 16 + e];
    lrunf += src[32];
  }
  LGKM_DRAIN();     // combine reads retired before ctile overwrites the slice

  // --- epilogue: cross-half rowsum, normalize, coalesced store via LDS ---
  float ls = lrunf + __shfl_xor(lrunf, 32);   // full rowsum for q = l32
  float rinv = __builtin_amdgcn_rcpf(ls);
  uint16_t* ctile = (uint16_t*)(smem + wq * 8448);   // own cacc slice
#pragma unroll
  for (int e = 0; e < 16; ++e) {
    int qe = (e & 3) + 8 * (e >> 2) + 4 * hi;   // q-row of this acc reg
    float rv = __shfl(rinv, qe);
    ctile[qe * 72 + l32]      = f2bf_u(acc[0][e] * rv);
    ctile[qe * 72 + 32 + l32] = f2bf_u(acc[1][e] * rv);
  }
  LGKM_DRAIN();
  {
    const int q8 = lane >> 3, d0 = (lane & 7) * 8;
    const int gcb = (head >> 1) * HN;
#pragma unroll
    for (int it = 0; it < 4; ++it) {
      int ql = it * 8 + q8;
      bf16x8 vv = ldb8(ctile + ql * 72 + d0);
      int row = 2 * (q0w + ql) + (head & 1);    // reference (nh,b) view scramble
      *(bf16x8*)(ctxb + (size_t)row * H + gcb + d0) = vv;
    }
  }
}

// ---------------------------------------------------------------------------
// Kernel 4: projection + bias.  (round-7 version: depth-3 counted-vmcnt)
// ---------------------------------------------------------------------------
__global__ __launch_bounds__(256) void gemm_proj_kernel(
    const uint16_t* __restrict__ ab, const uint16_t* __restrict__ wb,
    const float* __restrict__ bias, float* __restrict__ out) {
  const int lane = threadIdx.x & 63;
  const int wave = threadIdx.x >> 6;
  const int quad = lane >> 4, l16 = lane & 15;
  const int row0 = blockIdx.y * 128, col0 = blockIdx.x * 64;

  // buf b: sA 128x32 (8 KB) + sB 64x32 (4 KB) at smem + b*12288; 3 bufs.
  __shared__ __align__(16) char smem[3 * 12288];

  const int lrow = lane >> 2;
  const int lk   = (lane & 3) * 8;

  f32x4 acc[2][4];
#pragma unroll
  for (int i = 0; i < 2; ++i)
#pragma unroll
    for (int j = 0; j < 4; ++j) acc[i][j] = (f32x4){0.f, 0.f, 0.f, 0.f};

  auto STAGE = [&](int b, int k0) {   // 3 gll16 per wave
    uint16_t* sA = (uint16_t*)(smem + b * 12288);
    uint16_t* sB = sA + 4096;
#pragma unroll
    for (int c = 0; c < 2; ++c) {
      int g = c * 4 + wave;
      gll16(ab + (size_t)(row0 + g * 16 + lrow) * H + k0 + lk, sA + g * 512);
    }
    gll16(wb + (size_t)(col0 + wave * 16 + lrow) * H + k0 + lk, sB + wave * 512);
  };

  auto COMPUTE = [&](int b) {
    const uint16_t* sA = (const uint16_t*)(smem + b * 12288);
    const uint16_t* sB = sA + 4096;
    bf16x8 af[2], bfr[4];
#pragma unroll
    for (int mt = 0; mt < 2; ++mt)
      af[mt] = ldb8(sA + (wave * 32 + mt * 16 + l16) * 32 + quad * 8);
#pragma unroll
    for (int nt = 0; nt < 4; ++nt)
      bfr[nt] = ldb8(sB + (nt * 16 + l16) * 32 + quad * 8);
    __builtin_amdgcn_s_setprio(1);
#pragma unroll
    for (int mt = 0; mt < 2; ++mt)
#pragma unroll
      for (int nt = 0; nt < 4; ++nt)
        acc[mt][nt] = MFMA16(af[mt], bfr[nt], acc[mt][nt]);
    __builtin_amdgcn_s_setprio(0);
    asm volatile("s_waitcnt lgkmcnt(0)" ::: "memory");
    __builtin_amdgcn_s_barrier();
  };

  STAGE(0, 0);
  STAGE(1, 32);
  STAGE(2, 64);

#pragma unroll 3
  for (int t = 0; t < 30; ++t) {
    asm volatile("s_waitcnt vmcnt(6)" ::: "memory");   // oldest tile landed
    __builtin_amdgcn_s_barrier();
    COMPUTE(t % 3);
    if (t < 29) STAGE(t % 3, (t + 3) * 32);
  }
  asm volatile("s_waitcnt vmcnt(3)" ::: "memory");
  __builtin_amdgcn_s_barrier();
  COMPUTE(0);                                          // tile 30
  asm volatile("s_waitcnt vmcnt(0)" ::: "memory");
  __builtin_amdgcn_s_barrier();
  COMPUTE(1);                                          // tile 31

#pragma unroll
  for (int mt = 0; mt < 2; ++mt)
#pragma unroll
    for (int nt = 0; nt < 4; ++nt)
#pragma unroll
      for (int r = 0; r < 4; ++r) {
        int m = row0 + wave * 32 + mt * 16 + quad * 4 + r;  // t' = s*2+bi
        int c = col0 + nt * 16 + l16;
        int s = m >> 1, bi = m & 1;
        out[(size_t)(bi * SQ + s) * H + c] = acc[mt][nt][r] + bias[c];
      }
}

// ---------------------------------------------------------------------------
extern "C" void kernel_launch(void* const* d_in, const int* in_sizes, int n_in,
                              void* d_out, int out_size, void* d_ws, size_t ws_size,
                              hipStream_t stream) {
  const float* x     = (const float*)d_in[0];
  const float* wqkv  = (const float*)d_in[3];
  const float* wproj = (const float*)d_in[4];
  const float* bproj = (const float*)d_in[5];
  float* out = (float*)d_out;

  char* ws = (char*)d_ws;
  uint16_t* xb     = (uint16_t*)(ws);                        //  8 MB
  uint16_t* wqkvb  = (uint16_t*)(ws + (8ull  << 20));        //  6 MB
  uint16_t* wprojb = (uint16_t*)(ws + (14ull << 20));        //  2 MB
  uint16_t* Qb     = (uint16_t*)(ws + (16ull << 20));        //  8 MB [32][2048][64] (pre-scaled)
  uint16_t* Kb     = (uint16_t*)(ws + (24ull << 20));        //  8 MB [32][2048][64]
  uint16_t* Vtb    = (uint16_t*)(ws + (32ull << 20));        //  8 MB [32][64][2048] (s-permuted)
  uint16_t* ctxb   = (uint16_t*)(ws + (40ull << 20));        //  8 MB [4096][1024]

  convert_kernel<<<8192, 256, 0, stream>>>(x, wqkv, wproj, xb, wqkvb, wprojb);
  gemm_qkv_kernel<<<dim3(N3H / 128, T_TOK / 128), 256, 0, stream>>>(xb, wqkvb, Qb, Kb, Vtb);
  attn_kernel<<<512, 512, 0, stream>>>(Qb, Kb, Vtb, ctxb);
  gemm_proj_kernel<<<dim3(H / 64, T_TOK / 128), 256, 0, stream>>>(ctxb, wprojb, bproj, out);
}

// Round 12
// 198.812 us; speedup vs baseline: 1.4070x; 1.0777x over previous
//
#include <hip/hip_runtime.h>
#include <stdint.h>

// Problem constants
#define B_   2
#define SQ   2048
#define H    1024
#define NH   16
#define HN   64
#define T_TOK 4096          // sq*b tokens
#define N3H  3072           // 3*h

typedef __bf16 bf16x8 __attribute__((ext_vector_type(8)));
typedef float  f32x4  __attribute__((ext_vector_type(4)));
typedef float  f32x16 __attribute__((ext_vector_type(16)));

#define MFMA16(a, b, c) __builtin_amdgcn_mfma_f32_16x16x32_bf16((a), (b), (c), 0, 0, 0)
#define MFMA32(a, b, c) __builtin_amdgcn_mfma_f32_32x32x16_bf16((a), (b), (c), 0, 0, 0)

// s_waitcnt lgkmcnt(0), vmcnt/expcnt left open (intrinsic form).
#define LGKM_DRAIN() do { \
  __builtin_amdgcn_s_waitcnt(0xC07F); \
  __builtin_amdgcn_wave_barrier(); \
} while (0)

__device__ __forceinline__ uint16_t f2bf_u(float f) {
  union { float f; uint32_t u; } v; v.f = f;
  uint32_t u = v.u;
  u += 0x7fffu + ((u >> 16) & 1u);   // RNE (no NaN inputs here)
  return (uint16_t)(u >> 16);
}

// packed f32 pair -> bf16 pair via compiler-native casts (RNE).
__device__ __forceinline__ uint32_t pk2(float a, float b) {
  union { __bf16 h[2]; uint32_t u; } r;
  r.h[0] = (__bf16)a;
  r.h[1] = (__bf16)b;
  return r.u;
}

__device__ __forceinline__ bf16x8 ldb8(const uint16_t* p) {
  return *reinterpret_cast<const bf16x8*>(p);
}

// async global->LDS, 16B per lane. LDS dest = wave-uniform base + lane*16.
__device__ __forceinline__ void gll16(const uint16_t* g, uint16_t* l) {
  __builtin_amdgcn_global_load_lds(
      (const __attribute__((address_space(1))) uint32_t*)g,
      (__attribute__((address_space(3))) uint32_t*)l, 16, 0, 0);
}

// ---------------------------------------------------------------------------
// Kernel 1: fp32 -> bf16, 4 elements/thread.  (unchanged)
// ---------------------------------------------------------------------------
__global__ __launch_bounds__(256) void convert_kernel(
    const float* __restrict__ x, const float* __restrict__ wqkv,
    const float* __restrict__ wproj,
    uint16_t* __restrict__ xb, uint16_t* __restrict__ wqkvb,
    uint16_t* __restrict__ wprojb) {
  const int XT4 = (T_TOK * H) / 4;   // 1048576
  const int WQ4 = (N3H * H) / 4;     // 786432
  int i4 = blockIdx.x * 256 + threadIdx.x;
  const float* src;
  uint16_t* dst;
  if (i4 < XT4) {
    int i = i4 * 4;
    int t = i >> 10, c = i & 1023;
    int bi = t & 1, s = t >> 1;
    src = x + (bi * SQ + s) * H + c;
    dst = xb + i;
  } else if (i4 < XT4 + WQ4) {
    int j = (i4 - XT4) * 4;
    src = wqkv + j; dst = wqkvb + j;
  } else {
    int j = (i4 - XT4 - WQ4) * 4;
    src = wproj + j; dst = wprojb + j;
  }
  float4 v = *(const float4*)src;
  ushort4 o;
  o.x = f2bf_u(v.x); o.y = f2bf_u(v.y); o.z = f2bf_u(v.z); o.w = f2bf_u(v.w);
  *(ushort4*)dst = o;
}

// ---------------------------------------------------------------------------
// Kernel 2: QKV GEMM.  (round-7 version, HW-verified: depth-3 counted-vmcnt
// pipeline; Q pre-scaled, Vtb s-permuted epilogue)
// ---------------------------------------------------------------------------
__global__ __launch_bounds__(256) void gemm_qkv_kernel(
    const uint16_t* __restrict__ xb, const uint16_t* __restrict__ wb,
    uint16_t* __restrict__ Qb, uint16_t* __restrict__ Kb,
    uint16_t* __restrict__ Vtb) {
  const int lane = threadIdx.x & 63;
  const int wave = threadIdx.x >> 6;
  const int quad = lane >> 4, l16 = lane & 15;
  const int wm = wave >> 1, wn = wave & 1;
  const int row0 = blockIdx.y * 128, col0 = blockIdx.x * 128;

  // buf b at smem + b*16384: {sA 128x32, sB 128x32}.  3 bufs = 48 KB.
  // Epilogue W (4 x 9728 B = 38912 B) overlays them after the loop.
  __shared__ __align__(16) char smem[3 * 16384];
  uint16_t* W = (uint16_t*)(smem) + wave * (64 * 76);

  const int lrow = lane >> 2;        // 0..15
  const int lk   = (lane & 3) * 8;   // k-chunk (8 elems = 16B)

  f32x4 acc[4][4];
#pragma unroll
  for (int i = 0; i < 4; ++i)
#pragma unroll
    for (int j = 0; j < 4; ++j) acc[i][j] = (f32x4){0.f, 0.f, 0.f, 0.f};

  auto STAGE = [&](int b, int k0) {   // 4 gll16 per wave
    uint16_t* sA = (uint16_t*)(smem + b * 16384);
    uint16_t* sB = sA + 4096;
#pragma unroll
    for (int c = 0; c < 2; ++c) {
      int g = c * 4 + wave;
      gll16(xb + (size_t)(row0 + g * 16 + lrow) * H + k0 + lk, sA + g * 512);
      gll16(wb + (size_t)(col0 + g * 16 + lrow) * H + k0 + lk, sB + g * 512);
    }
  };

  auto COMPUTE = [&](int b) {
    const uint16_t* sA = (const uint16_t*)(smem + b * 16384);
    const uint16_t* sB = sA + 4096;
    bf16x8 af[4], bfr[4];
#pragma unroll
    for (int mt = 0; mt < 4; ++mt)
      af[mt] = ldb8(sA + (wm * 64 + mt * 16 + l16) * 32 + quad * 8);
#pragma unroll
    for (int nt = 0; nt < 4; ++nt)
      bfr[nt] = ldb8(sB + (wn * 64 + nt * 16 + l16) * 32 + quad * 8);
    __builtin_amdgcn_s_setprio(1);
#pragma unroll
    for (int mt = 0; mt < 4; ++mt)
#pragma unroll
      for (int nt = 0; nt < 4; ++nt)
        acc[mt][nt] = MFMA16(af[mt], bfr[nt], acc[mt][nt]);
    __builtin_amdgcn_s_setprio(0);
    asm volatile("s_waitcnt lgkmcnt(0)" ::: "memory");   // reads complete
    __builtin_amdgcn_s_barrier();                        // before buf reuse
  };

  STAGE(0, 0);
  STAGE(1, 32);
  STAGE(2, 64);

#pragma unroll 3
  for (int t = 0; t < 30; ++t) {
    asm volatile("s_waitcnt vmcnt(8)" ::: "memory");   // oldest tile landed
    __builtin_amdgcn_s_barrier();
    COMPUTE(t % 3);
    if (t < 29) STAGE(t % 3, (t + 3) * 32);
  }
  asm volatile("s_waitcnt vmcnt(4)" ::: "memory");
  __builtin_amdgcn_s_barrier();
  COMPUTE(0);                                          // tile 30
  asm volatile("s_waitcnt vmcnt(0)" ::: "memory");
  __builtin_amdgcn_s_barrier();
  COMPUTE(1);                                          // tile 31 (trailing
                                                       // barrier guards W)

  const int c0 = col0 + wn * 64;       // 64-aligned
  const int cm = c0 >> 6;              // 0..47
  const int hd = cm / 3;               // head (compile-time magic-mul)
  const int which = cm - hd * 3;       // 0=Q 1=K 2=V
  const int t0 = row0 + wm * 64;

  if (which < 2) {
    const float qs = (which == 0) ? 0.18033688f : 1.0f;   // 0.125*log2(e) for Q
#pragma unroll
    for (int mt = 0; mt < 4; ++mt)
#pragma unroll
      for (int nt = 0; nt < 4; ++nt)
#pragma unroll
        for (int r = 0; r < 4; ++r)
          W[(mt * 16 + quad * 4 + r) * 76 + nt * 16 + l16] = f2bf_u(acc[mt][nt][r] * qs);
    LGKM_DRAIN();
    uint16_t* dstb = (which == 0) ? Qb : Kb;
    const int t8 = lane >> 3, d0 = (lane & 7) * 8;
#pragma unroll
    for (int it = 0; it < 8; ++it) {
      int tl = it * 8 + t8;
      int t = t0 + tl;
      int s = t >> 1;
      int n = (t & 1) * NH + hd;
      bf16x8 vv = ldb8(W + tl * 76 + d0);
      *(bf16x8*)(dstb + (size_t)(n * SQ + s) * HN + d0) = vv;
    }
  } else {
    // V: LDS tile [d][bi*32 + s_local] (logical s order), stride 76
    uint32_t* W32 = (uint32_t*)W;
#pragma unroll
    for (int mt = 0; mt < 4; ++mt)
#pragma unroll
      for (int nt = 0; nt < 4; ++nt) {
        int base = (nt * 16 + l16) * 76 + mt * 8 + quad * 2;   // even
        W32[base >> 1] =
            (uint32_t)f2bf_u(acc[mt][nt][0]) | ((uint32_t)f2bf_u(acc[mt][nt][2]) << 16);
        W32[(base >> 1) + 16] =
            (uint32_t)f2bf_u(acc[mt][nt][1]) | ((uint32_t)f2bf_u(acc[mt][nt][3]) << 16);
      }
    LGKM_DRAIN();
    // store with s-permutation pi(s) = swap bits 2,3 of s (self-inverse):
    // dest chunk sc (8 s') pulls source 4-groups {sb+4h+0..3, sb+4h+8..11}
    const int dl = lane >> 3;                 // 0..7
    const int bi = (lane >> 2) & 1;
    const int sc = (lane & 3) * 8;
    const int s0 = (row0 >> 1) + wm * 32;
    const int n = bi * NH + hd;
    const int sb = sc & ~15;
    const int hh = (sc >> 3) & 1;
#pragma unroll
    for (int it = 0; it < 8; ++it) {
      int d = it * 8 + dl;
      const uint16_t* Wr = W + d * 76 + bi * 32 + sb + hh * 4;
      union { uint64_t q[2]; bf16x8 v; } vv;
      vv.q[0] = *(const uint64_t*)(Wr);       // logical s: sb + 4h + 0..3
      vv.q[1] = *(const uint64_t*)(Wr + 8);   // logical s: sb + 4h + 8..11
      *(bf16x8*)(Vtb + (size_t)(n * HN + d) * SQ + s0 + sc) = vv.v;
    }
  }
}

// ---------------------------------------------------------------------------
// Kernel 3: flash attention.  Round-12: round-11 structure (single-buffered
// staging, 33.8 KB LDS) with __launch_bounds__(512) ONLY — no min-waves arg.
// r10 (512,8) and r11 (512,6) both made the allocator spill (true register
// need = ~52 arch-VGPR + 32 acc-AGPR ~ 84-90 unified regs > cap).  With no
// occupancy bound the compiler allocates naturally (r8 proved ~84 no-spill);
// hardware occupancy = min(LDS 4 blk/CU, VGPR ~5-6 waves/SIMD) ~ 3 blk/CU
// = 24 waves/CU, vs r8's 16.
// ---------------------------------------------------------------------------
__global__ __launch_bounds__(512) void attn_kernel(
    const uint16_t* __restrict__ Qb, const uint16_t* __restrict__ Kb,
    const uint16_t* __restrict__ Vtb, uint16_t* __restrict__ ctxb) {
  const int lane = threadIdx.x & 63;
  const int wave = threadIdx.x >> 6;        // 0..7
  const int l32 = lane & 31;
  const int hi  = lane >> 5;
  const int wq = wave & 3;                  // q-subtile (32 rows)
  const int hf = wave >> 2;                 // k-range half

  const int bid = blockIdx.x;               // 512 blocks
  const int xcd = bid & 7, slot = bid >> 3; // id%8 -> XCD round-robin
  const int head = xcd * 4 + (slot >> 4);   // 4 heads pinned per XCD
  const int qt   = slot & 15;
  const int q0w  = qt * 128 + wq * 32;

  const uint16_t* Qh = Qb + (size_t)head * SQ * HN;
  const uint16_t* Kh = Kb + (size_t)head * SQ * HN;
  const uint16_t* Vh = Vtb + (size_t)head * HN * SQ;

  // LDS: staging sK(hf)=smem+hf*16384 {K 8KB + V 8KB} = 32 KB total.
  // Epilogue cacc[4][64][33] f32 (33792 B) overlays staging; each wave's
  // ctile reuses its OWN cacc slice (read-then-write, same wave, drained).
  __shared__ __align__(16) char smem[33792];
  float (*cacc)[64][33] = (float(*)[64][33])smem;

  const int lr8 = lane >> 3, lc8 = lane & 7;
  const int sc8 = (lc8 - lr8) & 7;          // logical chunk this lane fetches

  // persistent Q fragments (B operand): col q = q0w + l32, k-half = hi
  bf16x8 qf[4];
#pragma unroll
  for (int dc = 0; dc < 4; ++dc)
    qf[dc] = ldb8(Qh + (size_t)(q0w + l32) * HN + dc * 16 + hi * 8);

  f32x16 acc[2];
#pragma unroll
  for (int dt = 0; dt < 2; ++dt)
#pragma unroll
    for (int e = 0; e < 16; ++e) acc[dt][e] = 0.f;
  float lrun = 0.f;

  uint16_t* sK = (uint16_t*)(smem + hf * 16384);
  uint16_t* sV = sK + 4096;

  // stage one K tile + one Vt tile (this wave's 16 rows of each)
  auto STAGE = [&](int kt) {
    const int kbase = (hf * 16 + kt) * 64;
#pragma unroll
    for (int j = 0; j < 2; ++j) {
      int rr = wq * 16 + j * 8;
      gll16(Kh + (size_t)(kbase + rr + lr8) * HN + sc8 * 8, sK + rr * 64);
      gll16(Vh + (size_t)(rr + lr8) * SQ + kbase + sc8 * 8, sV + rr * 64);
    }
  };

  // full kt compute: QK^T, softmax, PV for both ktiles (r8 core, verbatim)
  auto KTCOMP = [&]() {
#pragma unroll
    for (int ktile = 0; ktile < 2; ++ktile) {
      f32x16 s;
#pragma unroll
      for (int e = 0; e < 16; ++e) s[e] = 0.f;
      __builtin_amdgcn_s_setprio(1);
#pragma unroll
      for (int dc = 0; dc < 4; ++dc) {
        bf16x8 kf = ldb8(sK + (ktile * 32 + l32) * 64 + ((dc * 2 + hi + l32) & 7) * 8);
        s = MFMA32(kf, qf[dc], s);
      }
      __builtin_amdgcn_s_setprio(0);
      uint32_t c[8];
#pragma unroll
      for (int i = 0; i < 8; ++i) {
        float p0 = __builtin_amdgcn_exp2f(s[2 * i]);
        float p1 = __builtin_amdgcn_exp2f(s[2 * i + 1]);
        lrun += p0;
        lrun += p1;
        c[i] = pk2(p0, p1);
      }
      union { uint32_t u[4]; bf16x8 v; } pa0, pa1;
#pragma unroll
      for (int x = 0; x < 4; ++x) { pa0.u[x] = c[x]; pa1.u[x] = c[4 + x]; }
      __builtin_amdgcn_s_setprio(1);
#pragma unroll
      for (int dt = 0; dt < 2; ++dt) {
        bf16x8 v0 = ldb8(sV + (dt * 32 + l32) * 64 + ((ktile * 4 + 0 + hi + l32) & 7) * 8);
        bf16x8 v1 = ldb8(sV + (dt * 32 + l32) * 64 + ((ktile * 4 + 2 + hi + l32) & 7) * 8);
        acc[dt] = MFMA32(pa0.v, v0, acc[dt]);
        acc[dt] = MFMA32(pa1.v, v1, acc[dt]);
      }
      __builtin_amdgcn_s_setprio(0);
    }
  };

  for (int kt = 0; kt < 16; ++kt) {
    STAGE(kt);
    asm volatile("s_waitcnt vmcnt(0)" ::: "memory");   // my stage landed
    __builtin_amdgcn_s_barrier();                      // all stages landed
    KTCOMP();
    asm volatile("s_waitcnt lgkmcnt(0)" ::: "memory"); // my frag reads done
    __builtin_amdgcn_s_barrier();                      // before overwrite
  }

  float lrunf = lrun;

  // --- k-split combine (linear: no max-tracking) via aliased LDS ---
  if (hf) {
    float* dst = &cacc[wq][lane][0];
#pragma unroll
    for (int dt = 0; dt < 2; ++dt)
#pragma unroll
      for (int e = 0; e < 16; ++e) dst[dt * 16 + e] = acc[dt][e];
    dst[32] = lrunf;
  }
  __syncthreads();
  if (hf) return;
  {
    const float* src = &cacc[wq][lane][0];
#pragma unroll
    for (int dt = 0; dt < 2; ++dt)
#pragma unroll
      for (int e = 0; e < 16; ++e) acc[dt][e] += src[dt * 16 + e];
    lrunf += src[32];
  }
  LGKM_DRAIN();     // combine reads retired before ctile overwrites the slice

  // --- epilogue: cross-half rowsum, normalize, coalesced store via LDS ---
  float ls = lrunf + __shfl_xor(lrunf, 32);   // full rowsum for q = l32
  float rinv = __builtin_amdgcn_rcpf(ls);
  uint16_t* ctile = (uint16_t*)(smem + wq * 8448);   // own cacc slice
#pragma unroll
  for (int e = 0; e < 16; ++e) {
    int qe = (e & 3) + 8 * (e >> 2) + 4 * hi;   // q-row of this acc reg
    float rv = __shfl(rinv, qe);
    ctile[qe * 72 + l32]      = f2bf_u(acc[0][e] * rv);
    ctile[qe * 72 + 32 + l32] = f2bf_u(acc[1][e] * rv);
  }
  LGKM_DRAIN();
  {
    const int q8 = lane >> 3, d0 = (lane & 7) * 8;
    const int gcb = (head >> 1) * HN;
#pragma unroll
    for (int it = 0; it < 4; ++it) {
      int ql = it * 8 + q8;
      bf16x8 vv = ldb8(ctile + ql * 72 + d0);
      int row = 2 * (q0w + ql) + (head & 1);    // reference (nh,b) view scramble
      *(bf16x8*)(ctxb + (size_t)row * H + gcb + d0) = vv;
    }
  }
}

// ---------------------------------------------------------------------------
// Kernel 4: projection + bias.  (round-7 version: depth-3 counted-vmcnt)
// ---------------------------------------------------------------------------
__global__ __launch_bounds__(256) void gemm_proj_kernel(
    const uint16_t* __restrict__ ab, const uint16_t* __restrict__ wb,
    const float* __restrict__ bias, float* __restrict__ out) {
  const int lane = threadIdx.x & 63;
  const int wave = threadIdx.x >> 6;
  const int quad = lane >> 4, l16 = lane & 15;
  const int row0 = blockIdx.y * 128, col0 = blockIdx.x * 64;

  // buf b: sA 128x32 (8 KB) + sB 64x32 (4 KB) at smem + b*12288; 3 bufs.
  __shared__ __align__(16) char smem[3 * 12288];

  const int lrow = lane >> 2;
  const int lk   = (lane & 3) * 8;

  f32x4 acc[2][4];
#pragma unroll
  for (int i = 0; i < 2; ++i)
#pragma unroll
    for (int j = 0; j < 4; ++j) acc[i][j] = (f32x4){0.f, 0.f, 0.f, 0.f};

  auto STAGE = [&](int b, int k0) {   // 3 gll16 per wave
    uint16_t* sA = (uint16_t*)(smem + b * 12288);
    uint16_t* sB = sA + 4096;
#pragma unroll
    for (int c = 0; c < 2; ++c) {
      int g = c * 4 + wave;
      gll16(ab + (size_t)(row0 + g * 16 + lrow) * H + k0 + lk, sA + g * 512);
    }
    gll16(wb + (size_t)(col0 + wave * 16 + lrow) * H + k0 + lk, sB + wave * 512);
  };

  auto COMPUTE = [&](int b) {
    const uint16_t* sA = (const uint16_t*)(smem + b * 12288);
    const uint16_t* sB = sA + 4096;
    bf16x8 af[2], bfr[4];
#pragma unroll
    for (int mt = 0; mt < 2; ++mt)
      af[mt] = ldb8(sA + (wave * 32 + mt * 16 + l16) * 32 + quad * 8);
#pragma unroll
    for (int nt = 0; nt < 4; ++nt)
      bfr[nt] = ldb8(sB + (nt * 16 + l16) * 32 + quad * 8);
    __builtin_amdgcn_s_setprio(1);
#pragma unroll
    for (int mt = 0; mt < 2; ++mt)
#pragma unroll
      for (int nt = 0; nt < 4; ++nt)
        acc[mt][nt] = MFMA16(af[mt], bfr[nt], acc[mt][nt]);
    __builtin_amdgcn_s_setprio(0);
    asm volatile("s_waitcnt lgkmcnt(0)" ::: "memory");
    __builtin_amdgcn_s_barrier();
  };

  STAGE(0, 0);
  STAGE(1, 32);
  STAGE(2, 64);

#pragma unroll 3
  for (int t = 0; t < 30; ++t) {
    asm volatile("s_waitcnt vmcnt(6)" ::: "memory");   // oldest tile landed
    __builtin_amdgcn_s_barrier();
    COMPUTE(t % 3);
    if (t < 29) STAGE(t % 3, (t + 3) * 32);
  }
  asm volatile("s_waitcnt vmcnt(3)" ::: "memory");
  __builtin_amdgcn_s_barrier();
  COMPUTE(0);                                          // tile 30
  asm volatile("s_waitcnt vmcnt(0)" ::: "memory");
  __builtin_amdgcn_s_barrier();
  COMPUTE(1);                                          // tile 31

#pragma unroll
  for (int mt = 0; mt < 2; ++mt)
#pragma unroll
    for (int nt = 0; nt < 4; ++nt)
#pragma unroll
      for (int r = 0; r < 4; ++r) {
        int m = row0 + wave * 32 + mt * 16 + quad * 4 + r;  // t' = s*2+bi
        int c = col0 + nt * 16 + l16;
        int s = m >> 1, bi = m & 1;
        out[(size_t)(bi * SQ + s) * H + c] = acc[mt][nt][r] + bias[c];
      }
}

// ---------------------------------------------------------------------------
extern "C" void kernel_launch(void* const* d_in, const int* in_sizes, int n_in,
                              void* d_out, int out_size, void* d_ws, size_t ws_size,
                              hipStream_t stream) {
  const float* x     = (const float*)d_in[0];
  const float* wqkv  = (const float*)d_in[3];
  const float* wproj = (const float*)d_in[4];
  const float* bproj = (const float*)d_in[5];
  float* out = (float*)d_out;

  char* ws = (char*)d_ws;
  uint16_t* xb     = (uint16_t*)(ws);                        //  8 MB
  uint16_t* wqkvb  = (uint16_t*)(ws + (8ull  << 20));        //  6 MB
  uint16_t* wprojb = (uint16_t*)(ws + (14ull << 20));        //  2 MB
  uint16_t* Qb     = (uint16_t*)(ws + (16ull << 20));        //  8 MB [32][2048][64] (pre-scaled)
  uint16_t* Kb     = (uint16_t*)(ws + (24ull << 20));        //  8 MB [32][2048][64]
  uint16_t* Vtb    = (uint16_t*)(ws + (32ull << 20));        //  8 MB [32][64][2048] (s-permuted)
  uint16_t* ctxb   = (uint16_t*)(ws + (40ull << 20));        //  8 MB [4096][1024]

  convert_kernel<<<8192, 256, 0, stream>>>(x, wqkv, wproj, xb, wqkvb, wprojb);
  gemm_qkv_kernel<<<dim3(N3H / 128, T_TOK / 128), 256, 0, stream>>>(xb, wqkvb, Qb, Kb, Vtb);
  attn_kernel<<<512, 512, 0, stream>>>(Qb, Kb, Vtb, ctxb);
  gemm_proj_kernel<<<dim3(H / 64, T_TOK / 128), 256, 0, stream>>>(ctxb, wprojb, bproj, out);
}

// Round 13
// 195.889 us; speedup vs baseline: 1.4280x; 1.0149x over previous
//
#include <hip/hip_runtime.h>
#include <stdint.h>

// Problem constants
#define B_   2
#define SQ   2048
#define H    1024
#define NH   16
#define HN   64
#define T_TOK 4096          // sq*b tokens
#define N3H  3072           // 3*h

typedef __bf16 bf16x8 __attribute__((ext_vector_type(8)));
typedef float  f32x4  __attribute__((ext_vector_type(4)));
typedef float  f32x16 __attribute__((ext_vector_type(16)));

#define MFMA16(a, b, c) __builtin_amdgcn_mfma_f32_16x16x32_bf16((a), (b), (c), 0, 0, 0)
#define MFMA32(a, b, c) __builtin_amdgcn_mfma_f32_32x32x16_bf16((a), (b), (c), 0, 0, 0)

// s_waitcnt lgkmcnt(0), vmcnt/expcnt left open (intrinsic form).
#define LGKM_DRAIN() do { \
  __builtin_amdgcn_s_waitcnt(0xC07F); \
  __builtin_amdgcn_wave_barrier(); \
} while (0)

__device__ __forceinline__ uint16_t f2bf_u(float f) {
  union { float f; uint32_t u; } v; v.f = f;
  uint32_t u = v.u;
  u += 0x7fffu + ((u >> 16) & 1u);   // RNE (no NaN inputs here)
  return (uint16_t)(u >> 16);
}

// packed f32 pair -> bf16 pair via compiler-native casts (RNE).
__device__ __forceinline__ uint32_t pk2(float a, float b) {
  union { __bf16 h[2]; uint32_t u; } r;
  r.h[0] = (__bf16)a;
  r.h[1] = (__bf16)b;
  return r.u;
}

__device__ __forceinline__ bf16x8 ldb8(const uint16_t* p) {
  return *reinterpret_cast<const bf16x8*>(p);
}

// async global->LDS, 16B per lane. LDS dest = wave-uniform base + lane*16.
__device__ __forceinline__ void gll16(const uint16_t* g, uint16_t* l) {
  __builtin_amdgcn_global_load_lds(
      (const __attribute__((address_space(1))) uint32_t*)g,
      (__attribute__((address_space(3))) uint32_t*)l, 16, 0, 0);
}

// ---------------------------------------------------------------------------
// Kernel 1: fp32 -> bf16, 4 elements/thread.  (unchanged)
// ---------------------------------------------------------------------------
__global__ __launch_bounds__(256) void convert_kernel(
    const float* __restrict__ x, const float* __restrict__ wqkv,
    const float* __restrict__ wproj,
    uint16_t* __restrict__ xb, uint16_t* __restrict__ wqkvb,
    uint16_t* __restrict__ wprojb) {
  const int XT4 = (T_TOK * H) / 4;   // 1048576
  const int WQ4 = (N3H * H) / 4;     // 786432
  int i4 = blockIdx.x * 256 + threadIdx.x;
  const float* src;
  uint16_t* dst;
  if (i4 < XT4) {
    int i = i4 * 4;
    int t = i >> 10, c = i & 1023;
    int bi = t & 1, s = t >> 1;
    src = x + (bi * SQ + s) * H + c;
    dst = xb + i;
  } else if (i4 < XT4 + WQ4) {
    int j = (i4 - XT4) * 4;
    src = wqkv + j; dst = wqkvb + j;
  } else {
    int j = (i4 - XT4 - WQ4) * 4;
    src = wproj + j; dst = wprojb + j;
  }
  float4 v = *(const float4*)src;
  ushort4 o;
  o.x = f2bf_u(v.x); o.y = f2bf_u(v.y); o.z = f2bf_u(v.z); o.w = f2bf_u(v.w);
  *(ushort4*)dst = o;
}

// ---------------------------------------------------------------------------
// Kernel 2: QKV GEMM.  (round-7 version, HW-verified: depth-3 counted-vmcnt
// pipeline; Q pre-scaled, Vtb s-permuted epilogue)
// ---------------------------------------------------------------------------
__global__ __launch_bounds__(256) void gemm_qkv_kernel(
    const uint16_t* __restrict__ xb, const uint16_t* __restrict__ wb,
    uint16_t* __restrict__ Qb, uint16_t* __restrict__ Kb,
    uint16_t* __restrict__ Vtb) {
  const int lane = threadIdx.x & 63;
  const int wave = threadIdx.x >> 6;
  const int quad = lane >> 4, l16 = lane & 15;
  const int wm = wave >> 1, wn = wave & 1;
  const int row0 = blockIdx.y * 128, col0 = blockIdx.x * 128;

  // buf b at smem + b*16384: {sA 128x32, sB 128x32}.  3 bufs = 48 KB.
  // Epilogue W (4 x 9728 B = 38912 B) overlays them after the loop.
  __shared__ __align__(16) char smem[3 * 16384];
  uint16_t* W = (uint16_t*)(smem) + wave * (64 * 76);

  const int lrow = lane >> 2;        // 0..15
  const int lk   = (lane & 3) * 8;   // k-chunk (8 elems = 16B)

  f32x4 acc[4][4];
#pragma unroll
  for (int i = 0; i < 4; ++i)
#pragma unroll
    for (int j = 0; j < 4; ++j) acc[i][j] = (f32x4){0.f, 0.f, 0.f, 0.f};

  auto STAGE = [&](int b, int k0) {   // 4 gll16 per wave
    uint16_t* sA = (uint16_t*)(smem + b * 16384);
    uint16_t* sB = sA + 4096;
#pragma unroll
    for (int c = 0; c < 2; ++c) {
      int g = c * 4 + wave;
      gll16(xb + (size_t)(row0 + g * 16 + lrow) * H + k0 + lk, sA + g * 512);
      gll16(wb + (size_t)(col0 + g * 16 + lrow) * H + k0 + lk, sB + g * 512);
    }
  };

  auto COMPUTE = [&](int b) {
    const uint16_t* sA = (const uint16_t*)(smem + b * 16384);
    const uint16_t* sB = sA + 4096;
    bf16x8 af[4], bfr[4];
#pragma unroll
    for (int mt = 0; mt < 4; ++mt)
      af[mt] = ldb8(sA + (wm * 64 + mt * 16 + l16) * 32 + quad * 8);
#pragma unroll
    for (int nt = 0; nt < 4; ++nt)
      bfr[nt] = ldb8(sB + (wn * 64 + nt * 16 + l16) * 32 + quad * 8);
    __builtin_amdgcn_s_setprio(1);
#pragma unroll
    for (int mt = 0; mt < 4; ++mt)
#pragma unroll
      for (int nt = 0; nt < 4; ++nt)
        acc[mt][nt] = MFMA16(af[mt], bfr[nt], acc[mt][nt]);
    __builtin_amdgcn_s_setprio(0);
    asm volatile("s_waitcnt lgkmcnt(0)" ::: "memory");   // reads complete
    __builtin_amdgcn_s_barrier();                        // before buf reuse
  };

  STAGE(0, 0);
  STAGE(1, 32);
  STAGE(2, 64);

#pragma unroll 3
  for (int t = 0; t < 30; ++t) {
    asm volatile("s_waitcnt vmcnt(8)" ::: "memory");   // oldest tile landed
    __builtin_amdgcn_s_barrier();
    COMPUTE(t % 3);
    if (t < 29) STAGE(t % 3, (t + 3) * 32);
  }
  asm volatile("s_waitcnt vmcnt(4)" ::: "memory");
  __builtin_amdgcn_s_barrier();
  COMPUTE(0);                                          // tile 30
  asm volatile("s_waitcnt vmcnt(0)" ::: "memory");
  __builtin_amdgcn_s_barrier();
  COMPUTE(1);                                          // tile 31 (trailing
                                                       // barrier guards W)

  const int c0 = col0 + wn * 64;       // 64-aligned
  const int cm = c0 >> 6;              // 0..47
  const int hd = cm / 3;               // head (compile-time magic-mul)
  const int which = cm - hd * 3;       // 0=Q 1=K 2=V
  const int t0 = row0 + wm * 64;

  if (which < 2) {
    const float qs = (which == 0) ? 0.18033688f : 1.0f;   // 0.125*log2(e) for Q
#pragma unroll
    for (int mt = 0; mt < 4; ++mt)
#pragma unroll
      for (int nt = 0; nt < 4; ++nt)
#pragma unroll
        for (int r = 0; r < 4; ++r)
          W[(mt * 16 + quad * 4 + r) * 76 + nt * 16 + l16] = f2bf_u(acc[mt][nt][r] * qs);
    LGKM_DRAIN();
    uint16_t* dstb = (which == 0) ? Qb : Kb;
    const int t8 = lane >> 3, d0 = (lane & 7) * 8;
#pragma unroll
    for (int it = 0; it < 8; ++it) {
      int tl = it * 8 + t8;
      int t = t0 + tl;
      int s = t >> 1;
      int n = (t & 1) * NH + hd;
      bf16x8 vv = ldb8(W + tl * 76 + d0);
      *(bf16x8*)(dstb + (size_t)(n * SQ + s) * HN + d0) = vv;
    }
  } else {
    // V: LDS tile [d][bi*32 + s_local] (logical s order), stride 76
    uint32_t* W32 = (uint32_t*)W;
#pragma unroll
    for (int mt = 0; mt < 4; ++mt)
#pragma unroll
      for (int nt = 0; nt < 4; ++nt) {
        int base = (nt * 16 + l16) * 76 + mt * 8 + quad * 2;   // even
        W32[base >> 1] =
            (uint32_t)f2bf_u(acc[mt][nt][0]) | ((uint32_t)f2bf_u(acc[mt][nt][2]) << 16);
        W32[(base >> 1) + 16] =
            (uint32_t)f2bf_u(acc[mt][nt][1]) | ((uint32_t)f2bf_u(acc[mt][nt][3]) << 16);
      }
    LGKM_DRAIN();
    // store with s-permutation pi(s) = swap bits 2,3 of s (self-inverse):
    // dest chunk sc (8 s') pulls source 4-groups {sb+4h+0..3, sb+4h+8..11}
    const int dl = lane >> 3;                 // 0..7
    const int bi = (lane >> 2) & 1;
    const int sc = (lane & 3) * 8;
    const int s0 = (row0 >> 1) + wm * 32;
    const int n = bi * NH + hd;
    const int sb = sc & ~15;
    const int hh = (sc >> 3) & 1;
#pragma unroll
    for (int it = 0; it < 8; ++it) {
      int d = it * 8 + dl;
      const uint16_t* Wr = W + d * 76 + bi * 32 + sb + hh * 4;
      union { uint64_t q[2]; bf16x8 v; } vv;
      vv.q[0] = *(const uint64_t*)(Wr);       // logical s: sb + 4h + 0..3
      vv.q[1] = *(const uint64_t*)(Wr + 8);   // logical s: sb + 4h + 8..11
      *(bf16x8*)(Vtb + (size_t)(n * HN + d) * SQ + s0 + sc) = vv.v;
    }
  }
}

// ---------------------------------------------------------------------------
// Kernel 3: flash attention.  Round-13 = round-8 structure verbatim (dbuf
// 64 KB, counted-vmcnt loop — best measured attn, 45.6 µs) with ONE change:
// the LDS chunk swizzle gains a (row>>3) term — phys = (c + r + (r>>3))&7 —
// so lanes {l, l+8, l+16, l+24} (which previously shared one 4-bank chunk,
// the measured constant 4-way conflict = 4.23M cycles) land in DISTINCT
// chunks.  Pure permutation; staging source swizzle gains wave-uniform
// -(wq*2+j); read addrs use precomputed lsw = l32 + (l32>>3) (same op count).
// ---------------------------------------------------------------------------
__global__ __launch_bounds__(512, 4) void attn_kernel(
    const uint16_t* __restrict__ Qb, const uint16_t* __restrict__ Kb,
    const uint16_t* __restrict__ Vtb, uint16_t* __restrict__ ctxb) {
  const int lane = threadIdx.x & 63;
  const int wave = threadIdx.x >> 6;        // 0..7
  const int l32 = lane & 31;
  const int hi  = lane >> 5;
  const int wq = wave & 3;                  // q-subtile (32 rows)
  const int hf = wave >> 2;                 // k-range half

  const int bid = blockIdx.x;               // 512 blocks
  const int xcd = bid & 7, slot = bid >> 3; // id%8 -> XCD round-robin
  const int head = xcd * 4 + (slot >> 4);   // 4 heads pinned per XCD
  const int qt   = slot & 15;
  const int q0w  = qt * 128 + wq * 32;

  const uint16_t* Qh = Qb + (size_t)head * SQ * HN;
  const uint16_t* Kh = Kb + (size_t)head * SQ * HN;
  const uint16_t* Vh = Vtb + (size_t)head * HN * SQ;

  __shared__ __align__(16) char smem[65536];
  float (*cacc)[64][33] = (float(*)[64][33])smem;

  const int lr8 = lane >> 3, lc8 = lane & 7;
  const int lsw = l32 + (l32 >> 3);         // read-side swizzle term

  // persistent Q fragments (B operand): col q = q0w + l32, k-half = hi
  bf16x8 qf[4];
#pragma unroll
  for (int dc = 0; dc < 4; ++dc)
    qf[dc] = ldb8(Qh + (size_t)(q0w + l32) * HN + dc * 16 + hi * 8);

  f32x16 acc[2];
#pragma unroll
  for (int dt = 0; dt < 2; ++dt)
#pragma unroll
    for (int e = 0; e < 16; ++e) acc[dt][e] = 0.f;
  float lrun = 0.f;

  // stage one K tile + one Vt tile (this wave's 16 rows of each) into buf b
  // phys chunk p of row r holds logical chunk (p - r - (r>>3))&7
  auto STAGE = [&](int b, int kt) {
    uint16_t* sK = (uint16_t*)(smem + hf * 32768 + b * 16384);
    uint16_t* sV = sK + 4096;
    const int kbase = (hf * 16 + kt) * 64;
#pragma unroll
    for (int j = 0; j < 2; ++j) {
      int rr = wq * 16 + j * 8;
      int scj = (lc8 - lr8 - (wq * 2 + j)) & 7;   // logical chunk to fetch
      gll16(Kh + (size_t)(kbase + rr + lr8) * HN + scj * 8, sK + rr * 64);
      gll16(Vh + (size_t)(rr + lr8) * SQ + kbase + scj * 8, sV + rr * 64);
    }
  };

  // full kt compute: QK^T, softmax, PV for both ktiles of buffer b
  auto KTCOMP = [&](int b) {
    const uint16_t* sK = (const uint16_t*)(smem + hf * 32768 + b * 16384);
    const uint16_t* sV = sK + 4096;
#pragma unroll
    for (int ktile = 0; ktile < 2; ++ktile) {
      // --- S^T tile = K . Q^T : row = k_local, col = q (pre-scaled Q) ---
      f32x16 s;
#pragma unroll
      for (int e = 0; e < 16; ++e) s[e] = 0.f;
      __builtin_amdgcn_s_setprio(1);
#pragma unroll
      for (int dc = 0; dc < 4; ++dc) {
        bf16x8 kf = ldb8(sK + (ktile * 32 + l32) * 64 +
                         ((dc * 2 + hi + lsw + ktile * 4) & 7) * 8);
        s = MFMA32(kf, qf[dc], s);
      }
      __builtin_amdgcn_s_setprio(0);
      // --- softmax (exp2-domain, linear); lane owns q=l32's 16 k-slots ---
      uint32_t c[8];
#pragma unroll
      for (int i = 0; i < 8; ++i) {
        float p0 = __builtin_amdgcn_exp2f(s[2 * i]);
        float p1 = __builtin_amdgcn_exp2f(s[2 * i + 1]);
        lrun += p0;
        lrun += p1;
        c[i] = pk2(p0, p1);
      }
      // P fragments directly (V's s-permutation absorbs the k reorder)
      union { uint32_t u[4]; bf16x8 v; } pa0, pa1;
#pragma unroll
      for (int x = 0; x < 4; ++x) { pa0.u[x] = c[x]; pa1.u[x] = c[4 + x]; }
      // --- ctx += P @ V ---
      __builtin_amdgcn_s_setprio(1);
#pragma unroll
      for (int dt = 0; dt < 2; ++dt) {
        bf16x8 v0 = ldb8(sV + (dt * 32 + l32) * 64 +
                         ((ktile * 4 + 0 + hi + lsw + dt * 4) & 7) * 8);
        bf16x8 v1 = ldb8(sV + (dt * 32 + l32) * 64 +
                         ((ktile * 4 + 2 + hi + lsw + dt * 4) & 7) * 8);
        acc[dt] = MFMA32(pa0.v, v0, acc[dt]);
        acc[dt] = MFMA32(pa1.v, v1, acc[dt]);
      }
      __builtin_amdgcn_s_setprio(0);
    }
  };

  STAGE(0, 0);

#pragma unroll 2
  for (int kt = 0; kt < 15; ++kt) {
    const int cur = kt & 1;
    STAGE(cur ^ 1, kt + 1);                            // next tile in flight
    asm volatile("s_waitcnt vmcnt(4)" ::: "memory");   // current tile landed
    __builtin_amdgcn_s_barrier();
    KTCOMP(cur);
    asm volatile("s_waitcnt lgkmcnt(0)" ::: "memory"); // my frag reads done
    __builtin_amdgcn_s_barrier();                      // before buf overwrite
  }
  asm volatile("s_waitcnt vmcnt(0)" ::: "memory");     // final tile (no stage)
  __builtin_amdgcn_s_barrier();
  KTCOMP(1);
  asm volatile("s_waitcnt lgkmcnt(0)" ::: "memory");
  __builtin_amdgcn_s_barrier();                        // before cacc aliasing

  // --- k-split combine (linear: no max-tracking) via aliased LDS ---
  if (hf) {
    float* dst = &cacc[wq][lane][0];
#pragma unroll
    for (int dt = 0; dt < 2; ++dt)
#pragma unroll
      for (int e = 0; e < 16; ++e) dst[dt * 16 + e] = acc[dt][e];
    dst[32] = lrun;
  }
  __syncthreads();
  if (hf) return;
  {
    const float* src = &cacc[wq][lane][0];
#pragma unroll
    for (int dt = 0; dt < 2; ++dt)
#pragma unroll
      for (int e = 0; e < 16; ++e) acc[dt][e] += src[dt * 16 + e];
    lrun += src[32];
  }

  // --- epilogue: cross-half rowsum, normalize, coalesced store via LDS ---
  float ls = lrun + __shfl_xor(lrun, 32);   // full rowsum for q = l32
  float rinv = __builtin_amdgcn_rcpf(ls);
  uint16_t* ctile = (uint16_t*)(smem + 36864) + wq * (32 * 72);
#pragma unroll
  for (int e = 0; e < 16; ++e) {
    int qe = (e & 3) + 8 * (e >> 2) + 4 * hi;   // q-row of this acc reg
    float rv = __shfl(rinv, qe);
    ctile[qe * 72 + l32]      = f2bf_u(acc[0][e] * rv);
    ctile[qe * 72 + 32 + l32] = f2bf_u(acc[1][e] * rv);
  }
  LGKM_DRAIN();
  {
    const int q8 = lane >> 3, d0 = (lane & 7) * 8;
    const int gcb = (head >> 1) * HN;
#pragma unroll
    for (int it = 0; it < 4; ++it) {
      int ql = it * 8 + q8;
      bf16x8 vv = ldb8(ctile + ql * 72 + d0);
      int row = 2 * (q0w + ql) + (head & 1);    // reference (nh,b) view scramble
      *(bf16x8*)(ctxb + (size_t)row * H + gcb + d0) = vv;
    }
  }
}

// ---------------------------------------------------------------------------
// Kernel 4: projection + bias.  (round-7 version: depth-3 counted-vmcnt)
// ---------------------------------------------------------------------------
__global__ __launch_bounds__(256) void gemm_proj_kernel(
    const uint16_t* __restrict__ ab, const uint16_t* __restrict__ wb,
    const float* __restrict__ bias, float* __restrict__ out) {
  const int lane = threadIdx.x & 63;
  const int wave = threadIdx.x >> 6;
  const int quad = lane >> 4, l16 = lane & 15;
  const int row0 = blockIdx.y * 128, col0 = blockIdx.x * 64;

  // buf b: sA 128x32 (8 KB) + sB 64x32 (4 KB) at smem + b*12288; 3 bufs.
  __shared__ __align__(16) char smem[3 * 12288];

  const int lrow = lane >> 2;
  const int lk   = (lane & 3) * 8;

  f32x4 acc[2][4];
#pragma unroll
  for (int i = 0; i < 2; ++i)
#pragma unroll
    for (int j = 0; j < 4; ++j) acc[i][j] = (f32x4){0.f, 0.f, 0.f, 0.f};

  auto STAGE = [&](int b, int k0) {   // 3 gll16 per wave
    uint16_t* sA = (uint16_t*)(smem + b * 12288);
    uint16_t* sB = sA + 4096;
#pragma unroll
    for (int c = 0; c < 2; ++c) {
      int g = c * 4 + wave;
      gll16(ab + (size_t)(row0 + g * 16 + lrow) * H + k0 + lk, sA + g * 512);
    }
    gll16(wb + (size_t)(col0 + wave * 16 + lrow) * H + k0 + lk, sB + wave * 512);
  };

  auto COMPUTE = [&](int b) {
    const uint16_t* sA = (const uint16_t*)(smem + b * 12288);
    const uint16_t* sB = sA + 4096;
    bf16x8 af[2], bfr[4];
#pragma unroll
    for (int mt = 0; mt < 2; ++mt)
      af[mt] = ldb8(sA + (wave * 32 + mt * 16 + l16) * 32 + quad * 8);
#pragma unroll
    for (int nt = 0; nt < 4; ++nt)
      bfr[nt] = ldb8(sB + (nt * 16 + l16) * 32 + quad * 8);
    __builtin_amdgcn_s_setprio(1);
#pragma unroll
    for (int mt = 0; mt < 2; ++mt)
#pragma unroll
      for (int nt = 0; nt < 4; ++nt)
        acc[mt][nt] = MFMA16(af[mt], bfr[nt], acc[mt][nt]);
    __builtin_amdgcn_s_setprio(0);
    asm volatile("s_waitcnt lgkmcnt(0)" ::: "memory");
    __builtin_amdgcn_s_barrier();
  };

  STAGE(0, 0);
  STAGE(1, 32);
  STAGE(2, 64);

#pragma unroll 3
  for (int t = 0; t < 30; ++t) {
    asm volatile("s_waitcnt vmcnt(6)" ::: "memory");   // oldest tile landed
    __builtin_amdgcn_s_barrier();
    COMPUTE(t % 3);
    if (t < 29) STAGE(t % 3, (t + 3) * 32);
  }
  asm volatile("s_waitcnt vmcnt(3)" ::: "memory");
  __builtin_amdgcn_s_barrier();
  COMPUTE(0);                                          // tile 30
  asm volatile("s_waitcnt vmcnt(0)" ::: "memory");
  __builtin_amdgcn_s_barrier();
  COMPUTE(1);                                          // tile 31

#pragma unroll
  for (int mt = 0; mt < 2; ++mt)
#pragma unroll
    for (int nt = 0; nt < 4; ++nt)
#pragma unroll
      for (int r = 0; r < 4; ++r) {
        int m = row0 + wave * 32 + mt * 16 + quad * 4 + r;  // t' = s*2+bi
        int c = col0 + nt * 16 + l16;
        int s = m >> 1, bi = m & 1;
        out[(size_t)(bi * SQ + s) * H + c] = acc[mt][nt][r] + bias[c];
      }
}

// ---------------------------------------------------------------------------
extern "C" void kernel_launch(void* const* d_in, const int* in_sizes, int n_in,
                              void* d_out, int out_size, void* d_ws, size_t ws_size,
                              hipStream_t stream) {
  const float* x     = (const float*)d_in[0];
  const float* wqkv  = (const float*)d_in[3];
  const float* wproj = (const float*)d_in[4];
  const float* bproj = (const float*)d_in[5];
  float* out = (float*)d_out;

  char* ws = (char*)d_ws;
  uint16_t* xb     = (uint16_t*)(ws);                        //  8 MB
  uint16_t* wqkvb  = (uint16_t*)(ws + (8ull  << 20));        //  6 MB
  uint16_t* wprojb = (uint16_t*)(ws + (14ull << 20));        //  2 MB
  uint16_t* Qb     = (uint16_t*)(ws + (16ull << 20));        //  8 MB [32][2048][64] (pre-scaled)
  uint16_t* Kb     = (uint16_t*)(ws + (24ull << 20));        //  8 MB [32][2048][64]
  uint16_t* Vtb    = (uint16_t*)(ws + (32ull << 20));        //  8 MB [32][64][2048] (s-permuted)
  uint16_t* ctxb   = (uint16_t*)(ws + (40ull << 20));        //  8 MB [4096][1024]

  convert_kernel<<<8192, 256, 0, stream>>>(x, wqkv, wproj, xb, wqkvb, wprojb);
  gemm_qkv_kernel<<<dim3(N3H / 128, T_TOK / 128), 256, 0, stream>>>(xb, wqkvb, Qb, Kb, Vtb);
  attn_kernel<<<512, 512, 0, stream>>>(Qb, Kb, Vtb, ctxb);
  gemm_proj_kernel<<<dim3(H / 64, T_TOK / 128), 256, 0, stream>>>(ctxb, wprojb, bproj, out);
}